// Round 1
// baseline (409.870 us; speedup 1.0000x reference)
//
#include <hip/hip_runtime.h>
#include <hip/hip_bf16.h>
#include <cstdint>
#include <cstddef>

// ---------------------------------------------------------------------------
// Shapes (compile-time constants for this problem)
// B=2, T=2048, D=1024, H=16, DH=64, CTX=2048.  M = B*T = 4096.
// ---------------------------------------------------------------------------

using bf16x8 = __attribute__((ext_vector_type(8))) __bf16;
using f32x4  = __attribute__((ext_vector_type(4))) float;

__device__ __forceinline__ short f2b(float f) {
  uint32_t u = __builtin_bit_cast(uint32_t, f);
  uint32_t r = (u + 0x7FFFu + ((u >> 16) & 1u)) >> 16;
  return (short)r;
}
__device__ __forceinline__ float b2f(short s) {
  uint32_t u = ((uint32_t)(uint16_t)s) << 16;
  return __builtin_bit_cast(float, u);
}

__device__ __forceinline__ void gload16(const short* g, short* l) {
  __builtin_amdgcn_global_load_lds(
      (const __attribute__((address_space(1))) void*)g,
      (__attribute__((address_space(3))) void*)l, 16, 0, 0);
}

// Stage ROWS x 64(bf16) tile into LDS, linear dest (global_load_lds needs
// uniform-base + lane*16), with XOR swizzle applied on the GLOBAL source so
// that LDS[row][seg] holds global segment (seg ^ (row&7)).  256 threads.
template<int ROWS>
__device__ __forceinline__ void stage_swz(const short* __restrict__ g, int ldg,
                                          short* lds, int tid) {
#pragma unroll
  for (int jj = 0; jj < ROWS / 32; ++jj) {
    int row = jj * 32 + (tid >> 3);
    int seg = tid & 7;
    int ss  = seg ^ (row & 7);
    gload16(g + (size_t)row * ldg + ss * 8, lds + row * 64 + (seg << 3));
  }
}

__device__ __forceinline__ f32x4 mma16(bf16x8 a, bf16x8 b, f32x4 c) {
  return __builtin_amdgcn_mfma_f32_16x16x32_bf16(a, b, c, 0, 0, 0);
}

// ---------------------------------------------------------------------------
// Elementwise: f32 -> bf16 convert (weights)
// ---------------------------------------------------------------------------
__global__ void k_cvt(const float* __restrict__ in, short* __restrict__ out, int n4) {
  int i = blockIdx.x * 256 + threadIdx.x;
  if (i < n4) {
    float4 v = ((const float4*)in)[i];
    short4 o = make_short4(f2b(v.x), f2b(v.y), f2b(v.z), f2b(v.w));
    ((short4*)out)[i] = o;
  }
}

// ---------------------------------------------------------------------------
// RMSNorm: one block (256 thr) per row of 1024 f32 -> bf16
// ---------------------------------------------------------------------------
__global__ void k_rms(const float* __restrict__ x, const float* __restrict__ w,
                      short* __restrict__ out) {
  int row = blockIdx.x;
  int tid = threadIdx.x;
  float4 v = *(const float4*)(x + (size_t)row * 1024 + tid * 4);
  float ss = v.x * v.x + v.y * v.y + v.z * v.z + v.w * v.w;
#pragma unroll
  for (int o = 1; o < 64; o <<= 1) ss += __shfl_xor(ss, o);
  __shared__ float sred[4];
  int wid = tid >> 6, lane = tid & 63;
  if (lane == 0) sred[wid] = ss;
  __syncthreads();
  float tot = sred[0] + sred[1] + sred[2] + sred[3];
  float r = rsqrtf(tot * (1.0f / 1024.0f) + 1e-6f);
  float4 wv = *(const float4*)(w + tid * 4);
  short4 o = make_short4(f2b(v.x * r * wv.x), f2b(v.y * r * wv.y),
                         f2b(v.z * r * wv.z), f2b(v.w * r * wv.w));
  *(short4*)(out + (size_t)row * 1024 + tid * 4) = o;
}

// ---------------------------------------------------------------------------
// bf16 NT GEMM: C[M,N] = A[M,K] * W[N,K]^T.  128x128 tile, BK=64, 4 waves.
// MODE 0: outf[m,n] = C + res[m,n]            (f32)
// MODE 1: outb[m,n] = bf16(C)                 (gate)
// MODE 2: outb[m,n] = bf16(silu(outb) * C)    (up, fused with gate)
// MODE 3: QKV epilogue -> q_b/k_b/vT_b bf16 + k/v caches f32
// ---------------------------------------------------------------------------
template<int MODE>
__global__ __launch_bounds__(256) void k_gemm(
    const short* __restrict__ A, const short* __restrict__ Bw,
    int M, int N, int K,
    float* __restrict__ outf, const float* __restrict__ res,
    short* __restrict__ outb,
    short* __restrict__ q_b, short* __restrict__ k_b, short* __restrict__ vT_b,
    float* __restrict__ kc, float* __restrict__ vc) {
  __shared__ short As[128 * 64];
  __shared__ short Bs[128 * 64];
  int tid = threadIdx.x;
  int m0 = blockIdx.y * 128, n0 = blockIdx.x * 128;
  int w = tid >> 6, l = tid & 63;
  int wr = w >> 1, wc = w & 1;
  f32x4 acc[4][4] = {};
  int nk = K >> 6;
  for (int kt = 0; kt < nk; ++kt) {
    int k0 = kt << 6;
    stage_swz<128>(A + (size_t)m0 * K + k0, K, As, tid);
    stage_swz<128>(Bw + (size_t)n0 * K + k0, K, Bs, tid);
    __syncthreads();
#pragma unroll
    for (int kk = 0; kk < 2; ++kk) {
      bf16x8 a[4], b[4];
      int sbase = kk * 4 + (l >> 4);
#pragma unroll
      for (int i = 0; i < 4; ++i) {
        int rowA = wr * 64 + i * 16 + (l & 15);
        a[i] = *(const bf16x8*)(As + rowA * 64 + ((sbase ^ (rowA & 7)) << 3));
        int rowB = wc * 64 + i * 16 + (l & 15);
        b[i] = *(const bf16x8*)(Bs + rowB * 64 + ((sbase ^ (rowB & 7)) << 3));
      }
#pragma unroll
      for (int i = 0; i < 4; ++i)
#pragma unroll
        for (int j = 0; j < 4; ++j)
          acc[i][j] = mma16(a[i], b[j], acc[i][j]);
    }
    __syncthreads();
  }
  // epilogue: C frag layout col = l&15, row = (l>>4)*4 + r
#pragma unroll
  for (int i = 0; i < 4; ++i) {
#pragma unroll
    for (int j = 0; j < 4; ++j) {
#pragma unroll
      for (int r = 0; r < 4; ++r) {
        int m = m0 + wr * 64 + i * 16 + (l >> 4) * 4 + r;
        int n = n0 + wc * 64 + j * 16 + (l & 15);
        float f = acc[i][j][r];
        if (MODE == 0) {
          outf[(size_t)m * N + n] = f + res[(size_t)m * N + n];
        } else if (MODE == 1) {
          outb[(size_t)m * N + n] = f2b(f);
        } else if (MODE == 2) {
          float g = b2f(outb[(size_t)m * N + n]);
          float s = g / (1.0f + __expf(-g));
          outb[(size_t)m * N + n] = f2b(s * f);
        } else {
          int jj = n >> 10, hh = (n >> 6) & 15, dh = n & 63;
          int b_ = m >> 11, t = m & 2047;
          int bh = b_ * 16 + hh;
          size_t idx = ((size_t)bh * 2048 + t) * 64 + dh;
          if (jj == 0) {
            q_b[idx] = f2b(f);
          } else if (jj == 1) {
            k_b[idx] = f2b(f);
            kc[idx] = f;
          } else {
            vT_b[((size_t)bh * 64 + dh) * 2048 + t] = f2b(f);
            vc[idx] = f;
          }
        }
      }
    }
  }
}

// ---------------------------------------------------------------------------
// Causal flash attention. Block = (qt, bh): 64 q rows, 4 waves x 16 q each.
// Swapped QK^T: S^T = mfma(K, Q) so per-lane q = l&15, keys = (l>>4)*4+r.
// P staged per-wave in padded LDS; V pre-transposed globally (vT_b).
// ---------------------------------------------------------------------------
__global__ __launch_bounds__(256) void k_attn(const short* __restrict__ q_b,
                                              const short* __restrict__ k_b,
                                              const short* __restrict__ vT_b,
                                              short* __restrict__ o_b) {
  __shared__ short Qs[64 * 64];
  __shared__ short Ks[64 * 64];
  __shared__ short VTs[64 * 64];
  __shared__ short Ps[4][16 * 88];
  int tid = threadIdx.x;
  int w = tid >> 6, l = tid & 63;
  int qt = blockIdx.x, bh = blockIdx.y;
  int q0 = qt * 64;

  stage_swz<64>(q_b + ((size_t)bh * 2048 + q0) * 64, 64, Qs, tid);

  f32x4 acc[4] = {};
  float mrow = -INFINITY, dden = 0.0f;
  int qg = q0 + w * 16 + (l & 15);
  int nt = qt + 1;

  for (int kt = 0; kt < nt; ++kt) {
    int kv0 = kt * 64;
    __syncthreads();  // prev tile's LDS reads done (and Q staged, kt==0)
    stage_swz<64>(k_b + ((size_t)bh * 2048 + kv0) * 64, 64, Ks, tid);
    stage_swz<64>(vT_b + (size_t)bh * 64 * 2048 + kv0, 2048, VTs, tid);
    __syncthreads();  // staged tiles visible

    // --- S^T = K * Q^T (per wave: 64 keys x 16 q)
    bf16x8 qf[2];
#pragma unroll
    for (int kk = 0; kk < 2; ++kk) {
      int rowq = w * 16 + (l & 15);
      int s = kk * 4 + (l >> 4);
      qf[kk] = *(const bf16x8*)(Qs + rowq * 64 + ((s ^ (rowq & 7)) << 3));
    }
    f32x4 st[4];
#pragma unroll
    for (int i = 0; i < 4; ++i) {
      f32x4 z = {};
#pragma unroll
      for (int kk = 0; kk < 2; ++kk) {
        int rowk = i * 16 + (l & 15);
        int s = kk * 4 + (l >> 4);
        bf16x8 kf = *(const bf16x8*)(Ks + rowk * 64 + ((s ^ (rowk & 7)) << 3));
        z = mma16(kf, qf[kk], z);
      }
      st[i] = z;
    }

    // --- online softmax (per lane: one q column, 16 of 64 keys local)
    float p[16];
    float pm = -INFINITY;
    bool last = (kt == qt);
#pragma unroll
    for (int i = 0; i < 4; ++i)
#pragma unroll
      for (int r = 0; r < 4; ++r) {
        int key = kv0 + i * 16 + (l >> 4) * 4 + r;
        float v = st[i][r] * 0.125f;
        if (last && key > qg) v = -INFINITY;
        p[i * 4 + r] = v;
        pm = fmaxf(pm, v);
      }
    pm = fmaxf(pm, __shfl_xor(pm, 16));
    pm = fmaxf(pm, __shfl_xor(pm, 32));
    float nm = fmaxf(mrow, pm);
    float corr = __expf(mrow - nm);
    float ds_ = 0.0f;
#pragma unroll
    for (int kx = 0; kx < 16; ++kx) {
      float pv = __expf(p[kx] - nm);
      p[kx] = pv;
      ds_ += pv;
    }
    ds_ += __shfl_xor(ds_, 16);
    ds_ += __shfl_xor(ds_, 32);
    dden = dden * corr + ds_;
    mrow = nm;
#pragma unroll
    for (int r = 0; r < 4; ++r) {
      float cr = __shfl(corr, (l >> 4) * 4 + r);
#pragma unroll
      for (int jf = 0; jf < 4; ++jf) acc[jf][r] *= cr;
    }

    // --- write P (bf16) to per-wave LDS: [q][key], ld=88
    short* pw = &Ps[w][0];
#pragma unroll
    for (int i = 0; i < 4; ++i) {
      uint32_t lo = (uint32_t)(uint16_t)f2b(p[i * 4 + 0]) |
                    ((uint32_t)(uint16_t)f2b(p[i * 4 + 1]) << 16);
      uint32_t hi = (uint32_t)(uint16_t)f2b(p[i * 4 + 2]) |
                    ((uint32_t)(uint16_t)f2b(p[i * 4 + 3]) << 16);
      uint2 pk;
      pk.x = lo;
      pk.y = hi;
      *(uint2*)(pw + (l & 15) * 88 + i * 16 + ((l >> 4) << 2)) = pk;
    }

    // --- PV: out[q, dh] += P[q, key] * V[key, dh]
#pragma unroll
    for (int kk = 0; kk < 2; ++kk) {
      bf16x8 pa = *(const bf16x8*)(pw + (l & 15) * 88 + kk * 32 + ((l >> 4) << 3));
#pragma unroll
      for (int jf = 0; jf < 4; ++jf) {
        int rowv = jf * 16 + (l & 15);
        int s = kk * 4 + (l >> 4);
        bf16x8 vb = *(const bf16x8*)(VTs + rowv * 64 + ((s ^ (rowv & 7)) << 3));
        acc[jf] = mma16(pa, vb, acc[jf]);
      }
    }
  }

  // --- epilogue: out frag layout col = dh = l&15, row = q = (l>>4)*4+r
  int hh = bh & 15, b_ = bh >> 4;
#pragma unroll
  for (int r = 0; r < 4; ++r) {
    float dq = __shfl(dden, (l >> 4) * 4 + r);
    float inv = 1.0f / dq;
    int mg = q0 + w * 16 + (l >> 4) * 4 + r;
    size_t rowoff = ((size_t)b_ * 2048 + mg) * 1024 + hh * 64;
#pragma unroll
    for (int jf = 0; jf < 4; ++jf)
      o_b[rowoff + jf * 16 + (l & 15)] = f2b(acc[jf][r] * inv);
  }
}

// ---------------------------------------------------------------------------
// Launch
// ---------------------------------------------------------------------------
extern "C" void kernel_launch(void* const* d_in, const int* in_sizes, int n_in,
                              void* d_out, int out_size, void* d_ws, size_t ws_size,
                              hipStream_t stream) {
  const float* x     = (const float*)d_in[0];
  const float* wn1   = (const float*)d_in[1];
  const float* wqkv  = (const float*)d_in[2];
  const float* wproj = (const float*)d_in[3];
  const float* wn2   = (const float*)d_in[4];
  const float* wgate = (const float*)d_in[5];
  const float* wup   = (const float*)d_in[6];
  const float* wdown = (const float*)d_in[7];
  float* out = (float*)d_out;
  char* ws = (char*)d_ws;

  // workspace layout (bytes)
  short* wqkv_b  = (short*)(ws + 0);         //  6 MB
  short* wproj_b = (short*)(ws + 6291456);   //  2 MB
  short* wgate_b = (short*)(ws + 8388608);   //  8 MB
  short* wup_b   = (short*)(ws + 16777216);  //  8 MB
  short* wdown_b = (short*)(ws + 25165824);  //  8 MB
  short* h_b     = (short*)(ws + 33554432);  //  8 MB (h, then h2)
  short* q_b     = (short*)(ws + 41943040);  //  8 MB
  short* k_b     = (short*)(ws + 50331648);  //  8 MB
  short* vT_b    = (short*)(ws + 58720256);  //  8 MB
  short* ao_b    = (short*)(ws + 67108864);  //  8 MB
  short* act_b   = q_b;   // 32 MB alias over q/k/vT/ao (free after attention)
  float* x1 = out;        // x1 lives in d_out[0..4M), overwritten in-place by GEMM4
  float* kc = out + 4194304;
  float* vc = out + 8388608;

  // weight conversions f32 -> bf16
  k_cvt<<<3072, 256, 0, stream>>>(wqkv, wqkv_b, 786432);
  k_cvt<<<1024, 256, 0, stream>>>(wproj, wproj_b, 262144);
  k_cvt<<<4096, 256, 0, stream>>>(wgate, wgate_b, 1048576);
  k_cvt<<<4096, 256, 0, stream>>>(wup, wup_b, 1048576);
  k_cvt<<<4096, 256, 0, stream>>>(wdown, wdown_b, 1048576);

  // h = rmsnorm(x)
  k_rms<<<4096, 256, 0, stream>>>(x, wn1, h_b);

  // qkv = h @ w_qkv^T  (writes q/k/vT bf16 + k/v caches f32)
  k_gemm<3><<<dim3(24, 32), 256, 0, stream>>>(h_b, wqkv_b, 4096, 3072, 1024,
                                              nullptr, nullptr, nullptr,
                                              q_b, k_b, vT_b, kc, vc);

  // attention
  k_attn<<<dim3(32, 32), 256, 0, stream>>>(q_b, k_b, vT_b, ao_b);

  // x1 = x + attn @ w_proj^T
  k_gemm<0><<<dim3(8, 32), 256, 0, stream>>>(ao_b, wproj_b, 4096, 1024, 1024,
                                             x1, x, nullptr,
                                             nullptr, nullptr, nullptr, nullptr, nullptr);

  // h2 = rmsnorm(x1)
  k_rms<<<4096, 256, 0, stream>>>(x1, wn2, h_b);

  // gate = h2 @ w_gate^T (bf16)
  k_gemm<1><<<dim3(32, 32), 256, 0, stream>>>(h_b, wgate_b, 4096, 4096, 1024,
                                              nullptr, nullptr, act_b,
                                              nullptr, nullptr, nullptr, nullptr, nullptr);
  // act = silu(gate) * (h2 @ w_up^T)
  k_gemm<2><<<dim3(32, 32), 256, 0, stream>>>(h_b, wup_b, 4096, 4096, 1024,
                                              nullptr, nullptr, act_b,
                                              nullptr, nullptr, nullptr, nullptr, nullptr);
  // x_out = x1 + act @ w_down^T   (in-place on d_out)
  k_gemm<0><<<dim3(8, 32), 256, 0, stream>>>(act_b, wdown_b, 4096, 1024, 4096,
                                             out, x1, nullptr,
                                             nullptr, nullptr, nullptr, nullptr, nullptr);
}